// Round 9
// baseline (271.193 us; speedup 1.0000x reference)
//
#include <hip/hip_runtime.h>

#define BATCH 4
#define CIN 64
#define HH 352
#define WW 1216
#define OCH 8
#define OHH 354
#define OWW 1218
#define HW (HH * WW)

#define PX 4        // cols per thread
#define TILE_W 64   // 16 tx * 4
#define TILE_H 8    // 8 ty rows, 1 output row per thread
#define NTHR 128

// Repack weights with BN folded in: w2[c*72 + (dh*3+dw)*8 + oc] = conv_w[oc][c][dh][dw] * scl[oc]
// bias at w2[4608 + oc] = beta - mean*scl
__global__ void repack_kernel(const float* __restrict__ conv_w,
                              const float* __restrict__ gamma,
                              const float* __restrict__ beta,
                              const float* __restrict__ mean,
                              const float* __restrict__ var,
                              float* __restrict__ w2)
{
    int tid = blockIdx.x * 256 + threadIdx.x;
    if (tid < CIN * 9 * OCH) {
        int ct = tid >> 3;   // c*9 + tap
        int oc = tid & 7;
        float scl = gamma[oc] * rsqrtf(var[oc] + 1e-5f);
        w2[tid] = conv_w[oc * (CIN * 9) + ct] * scl;
    }
    if (tid < OCH) {
        float scl = gamma[tid] * rsqrtf(var[tid] + 1e-5f);
        w2[CIN * 9 * OCH + tid] = beta[tid] - mean[tid] * scl;
    }
}

// Zero only the uncovered border of each (b,t) plane instead of 62 MB memset.
__global__ void border_kernel(float* __restrict__ out)
{
    const int bt = blockIdx.x;          // 0..35
    const int t = bt % 9;
    const int i = t / 3, j = t % 3;
    float* pl = out + (size_t)bt * OHH * OWW;
    const int r0 = (i == 0) ? HH : 0;
    const int r1 = (i == 2) ? 1 : (OHH - 1);
    const int c0 = (j == 0) ? WW : 0;
    const int c1 = (j == 2) ? 1 : (OWW - 1);
    const int nrow = 2 * OWW;
    for (int idx = threadIdx.x; idx < 2 * OWW + 2 * OHH; idx += blockDim.x) {
        if (idx < nrow) {
            int r = (idx < OWW) ? r0 : r1;
            int c = (idx < OWW) ? idx : idx - OWW;
            pl[(size_t)r * OWW + c] = 0.f;
        } else {
            int k = idx - nrow;
            int c = (k < OHH) ? c0 : c1;
            int r = (k < OHH) ? k : k - OHH;
            pl[(size_t)r * OWW + c] = 0.f;
        }
    }
}

__global__ __launch_bounds__(NTHR, 4)
void conv_kernel(const float* __restrict__ feature,
                 const float* __restrict__ w2all,
                 float* __restrict__ out)
{
    const int tid = threadIdx.x;
    const int tx = tid & 15, ty = tid >> 4;     // 16 x 8
    const int b  = blockIdx.z;
    const int h  = blockIdx.y * TILE_H + ty;    // this thread's output row
    const int w0 = blockIdx.x * TILE_W + tx * PX;

    const int   cl  = max(w0 - 1, 0);
    const int   cr  = min(w0 + 4, WW - 1);
    const float mvl = (w0 >= 1) ? 1.f : 0.f;
    const float mvr = (w0 + 4 < WW) ? 1.f : 0.f;

    int offc[3], offl[3], offr[3];
    float mc[3], ml[3], mr[3];
#pragma unroll
    for (int r = 0; r < 3; ++r) {
        int gh = h - 1 + r;
        bool rok = (unsigned)gh < (unsigned)HH;
        int sgh = min(max(gh, 0), HH - 1);
        offc[r] = sgh * WW + w0;
        offl[r] = sgh * WW + cl;
        offr[r] = sgh * WW + cr;
        mc[r] = rok ? 1.f : 0.f;
        ml[r] = mc[r] * mvl;
        mr[r] = mc[r] * mvr;
    }

    const float* fp = feature + (size_t)b * CIN * HW;

    float acc[PX][OCH];
#pragma unroll
    for (int p = 0; p < PX; ++p)
#pragma unroll
        for (int o = 0; o < OCH; ++o) acc[p][o] = 0.f;

#pragma unroll 1
    for (int c = 0; c < CIN; ++c) {
        const float* cb = fp + (size_t)c * HW;
        // 9 independent loads, issued together
        float4 m0 = *(const float4*)(cb + offc[0]);
        float4 m1 = *(const float4*)(cb + offc[1]);
        float4 m2 = *(const float4*)(cb + offc[2]);
        float l0 = cb[offl[0]], l1 = cb[offl[1]], l2 = cb[offl[2]];
        float r0 = cb[offr[0]], r1 = cb[offr[1]], r2 = cb[offr[2]];

        float f[3][6];
        f[0][0] = l0 * ml[0]; f[0][1] = m0.x * mc[0]; f[0][2] = m0.y * mc[0];
        f[0][3] = m0.z * mc[0]; f[0][4] = m0.w * mc[0]; f[0][5] = r0 * mr[0];
        f[1][0] = l1 * ml[1]; f[1][1] = m1.x * mc[1]; f[1][2] = m1.y * mc[1];
        f[1][3] = m1.z * mc[1]; f[1][4] = m1.w * mc[1]; f[1][5] = r1 * mr[1];
        f[2][0] = l2 * ml[2]; f[2][1] = m2.x * mc[2]; f[2][2] = m2.y * mc[2];
        f[2][3] = m2.z * mc[2]; f[2][4] = m2.w * mc[2]; f[2][5] = r2 * mr[2];

        const float* wc = w2all + c * 72;   // uniform -> s_load
#pragma unroll
        for (int dh = 0; dh < 3; ++dh)
#pragma unroll
            for (int dw = 0; dw < 3; ++dw)
#pragma unroll
                for (int o = 0; o < OCH; ++o) {
                    float wv = wc[(dh * 3 + dw) * OCH + o];
#pragma unroll
                    for (int p = 0; p < PX; ++p)
                        acc[p][o] = fmaf(f[dh][p + dw], wv, acc[p][o]);
                }
    }

    // Epilogue: bias, L1-normalize, mid, scatter 9 shifted planes.
    const float* bb = w2all + CIN * 9 * OCH;
    float sb[OCH];
#pragma unroll
    for (int o = 0; o < OCH; ++o) sb[o] = bb[o];

    float* ob = out + (size_t)b * 9 * OHH * OWW;
#pragma unroll
    for (int p = 0; p < PX; ++p) {
        const int w = w0 + p;
        float g[OCH];
        float asum = 0.f;
#pragma unroll
        for (int o = 0; o < OCH; ++o) {
            float v = acc[p][o] + sb[o];
            g[o] = v;
            asum += fabsf(v);
        }
        float inv = 1.0f / asum;
        float ss = 0.f;
#pragma unroll
        for (int o = 0; o < OCH; ++o) { g[o] *= inv; ss += g[o]; }
        float mid = 1.0f - ss;
#pragma unroll
        for (int t = 0; t < 9; ++t) {
            int i = t / 3, j = t - i * 3;
            float v = (t < 4) ? g[t] : ((t == 4) ? mid : g[t - 1]);
            ob[((size_t)t * OHH + (h + i)) * OWW + (w + j)] = v;
        }
    }
}

extern "C" void kernel_launch(void* const* d_in, const int* in_sizes, int n_in,
                              void* d_out, int out_size, void* d_ws, size_t ws_size,
                              hipStream_t stream) {
    const float* feature = (const float*)d_in[0];
    const float* conv_w  = (const float*)d_in[1];
    const float* gamma   = (const float*)d_in[2];
    const float* beta    = (const float*)d_in[3];
    const float* mean    = (const float*)d_in[4];
    const float* var     = (const float*)d_in[5];
    float* out = (float*)d_out;
    float* w2  = (float*)d_ws;   // 4608 + 8 floats

    border_kernel<<<BATCH * 9, 256, 0, stream>>>(out);
    repack_kernel<<<(CIN * 9 * OCH + 255) / 256, 256, 0, stream>>>(
        conv_w, gamma, beta, mean, var, w2);

    dim3 grid(WW / TILE_W, HH / TILE_H, BATCH);  // 19 x 44 x 4
    conv_kernel<<<grid, NTHR, 0, stream>>>(feature, w2, out);
}